// Round 18
// baseline (96.574 us; speedup 1.0000x reference)
//
#include <hip/hip_runtime.h>
#include <math.h>

#define NB 32
#define CIN 32
#define DIM 32
#define KK 5
#define VALID 17
#define CVOL (VALID*VALID*VALID)   // 4913
#define PROWS 36                   // rows per plane: row = ih+2; data rows 2..33; 34,35 zero;
                                   // "row 36" aliases next plane's zero row 0
#define PLNW (PROWS*32)            // 1152 words
#define SLABF (7*PLNW + 32)        // +32 tail pad = row 36 of plane 6; 8096 w = 32384 B -> 5 blocks/CU

// ws layout (floats): [0,4000) w_eff ; [4000] B ; [4096, ...) C partials [nsplit][32][4913]

__global__ __launch_bounds__(256) void prep_kernel(const float* __restrict__ weight,
                                                   const float* __restrict__ bias,
                                                   float* __restrict__ ws) {
    int idx = blockIdx.x * 256 + threadIdx.x;
    if (idx < 4000) {
        float s = 0.f;
        #pragma unroll 8
        for (int co = 0; co < 64; ++co) s += weight[co * 4000 + idx];
        ws[idx] = s;
    }
    if (idx == 0) {
        float b = 0.f;
        for (int i = 0; i < 64; ++i) b += bias[i];
        ws[4000] = b;
    }
}

__device__ __forceinline__ void gload_lds16(const float* g, float* l) {
    __builtin_amdgcn_global_load_lds((const __attribute__((address_space(1))) void*)g,
                                     (__attribute__((address_space(3))) void*)l,
                                     16, 0, 0);
}

// shfl_down-by-1: lane i <- lane i+1 via row_shl:1 (verified r16, absmax 0).
// CONVERGENCE RULE (r17 bug): must be called UNCONDITIONALLY in straight-line code.
// Wrapping it in `cond ? dpp(...) : 0` makes clang exec-mask the DPP region; a masked
// source lane then reads as 0 (bound_ctrl) -> lane wq=6 lost its taps (absmax 84).
__device__ __forceinline__ float dpp_shl1(float v) {
    return __int_as_float(__builtin_amdgcn_update_dpp(0, __float_as_int(v),
                                                      0x101 /*row_shl:1*/, 0xF, 0xF, true));
}

// Block = (split s, n, d-pair p). 128 threads: dq = tid>>6 (wave), hg = (tid>>3)&7, wq = tid&7.
// Thread outputs: d = 2p+dq; h = 2hg+hh (hg7: h14,15,16); w = 2wq+1, 2wq+2 (+ w=0 from wq0's accw0).
// BRANCHLESS compute: row-padded planes keep every read row (4hg+j in [0,36]) in-bounds;
// acc[2] computed by all lanes (stored only for tall); vb = DPP (all lanes) then cndmask-zero
// for wq7 (its true taps are zero-pad); accw0 unconditional. No branch wraps any ds_read.
// NOTE: no min-waves launch-bound arg — (128,4) forced VGPR=64 + scratch spill (round 10, 6x).
// NOTE: staging stays wave-uniform full-wave 16B/lane (lane<8 per-row variant was 2x slower, r13).
__global__ __launch_bounds__(128) void conv_kernel(const float* __restrict__ x,
                                                   const float* __restrict__ weff,
                                                   float* __restrict__ C,
                                                   int cpS) {
    __shared__ __align__(16) float slab[SLABF];
    const int b = blockIdx.x;
    const int s = b / (NB * 9);
    const int rem = b - s * (NB * 9);
    const int n = rem / 9;
    const int p = rem - n * 9;
    const int tid = threadIdx.x;
    const int dq = tid >> 6;          // wave index
    const int hg = (tid >> 3) & 7;
    const int wq = tid & 7;
    const int lane = tid & 63;
    const int d  = 2 * p + dq;
    const bool dok  = (d < VALID);
    const bool tall = (hg == 7);
    const bool w7ok = (wq < 7);
    const bool w0t  = (wq == 0);

    // zero slab once: pad rows + OOB planes must read as 0
    for (int t = tid; t < SLABF / 4; t += 128) ((float4*)slab)[t] = make_float4(0.f, 0.f, 0.f, 0.f);
    __syncthreads();

    const int id0 = 4 * p - 2;
    const int cin0 = s * cpS;

    float acc[3][2] = {{0.f,0.f},{0.f,0.f},{0.f,0.f}};
    float accw0[3]  = {0.f, 0.f, 0.f};

    for (int ci = 0; ci < cpS; ++ci) {
        // stage: 28 slots (7 planes x 4 chunks of 1KB, rows 2..33); wave-uniform dest
        const float* xc = x + ((size_t)n * CIN + (cin0 + ci)) * (DIM * DIM * DIM);
        #pragma unroll
        for (int st = 0; st < 14; ++st) {
            int slot = dq * 14 + st;          // wave-uniform
            int pi = slot >> 2, c = slot & 3;
            int id = id0 + pi;
            if (id >= 0 && id < DIM) {        // wave-uniform guard
                gload_lds16(xc + (size_t)id * 1024 + c * 256 + lane * 4,
                            slab + pi * PLNW + 64 + c * 256);
            }
        }
        __syncthreads();   // drains vmcnt: staged data visible

        const float* wb = weff + (cin0 + ci) * 125;
        #pragma unroll
        for (int kd = 0; kd < KK; ++kd) {
            const float* plane = slab + (2 * dq + kd) * PLNW;
            #pragma unroll
            for (int j = 0; j < 9; ++j) {
                // row 4hg+j in [0,36]: always in-bounds (pad rows / next-plane zeros)
                const float4 va = *(const float4*)(plane + (4 * hg + j) * 32 + 4 * wq);
                // DPP unconditional (all 64 lanes active), THEN zero-select (v_cndmask):
                const float t0 = dpp_shl1(va.x);
                const float t1 = dpp_shl1(va.y);
                const float t2 = dpp_shl1(va.z);
                const float vb0 = w7ok ? t0 : 0.f;   // iw 4wq+4 (wq7: zero-pad)
                const float vb1 = w7ok ? t1 : 0.f;   // iw 4wq+5
                const float vb2 = w7ok ? t2 : 0.f;   // iw 4wq+6
                #pragma unroll
                for (int hh = 0; hh < 3; ++hh) {
                    const int kh = j - 2 * hh;
                    if (kh >= 0 && kh < KK) {   // compile-time per (j,hh)
                        const float w0 = wb[kd * 25 + kh * 5 + 0];
                        const float w1 = wb[kd * 25 + kh * 5 + 1];
                        const float w2 = wb[kd * 25 + kh * 5 + 2];
                        const float w3 = wb[kd * 25 + kh * 5 + 3];
                        const float w4 = wb[kd * 25 + kh * 5 + 4];
                        acc[hh][0] = fmaf(w0, va.x, acc[hh][0]);
                        acc[hh][1] = fmaf(w0, va.z, acc[hh][1]);
                        acc[hh][0] = fmaf(w1, va.y, acc[hh][0]);
                        acc[hh][1] = fmaf(w1, va.w, acc[hh][1]);
                        acc[hh][0] = fmaf(w2, va.z, acc[hh][0]);
                        acc[hh][1] = fmaf(w2, vb0, acc[hh][1]);
                        acc[hh][0] = fmaf(w3, va.w, acc[hh][0]);
                        acc[hh][1] = fmaf(w3, vb1, acc[hh][1]);
                        acc[hh][0] = fmaf(w4, vb0, acc[hh][0]);
                        acc[hh][1] = fmaf(w4, vb2, acc[hh][1]);
                        // w=0 partial (only wq0's is stored): kw 2,3,4 hit iw 0,1,2
                        accw0[hh] = fmaf(w2, va.x, accw0[hh]);
                        accw0[hh] = fmaf(w3, va.y, accw0[hh]);
                        accw0[hh] = fmaf(w4, va.z, accw0[hh]);
                    }
                }
            }
        }
        __syncthreads();   // WAR: next stage overwrites slab
    }

    if (dok) {
        float* Cn = C + ((size_t)s * NB + n) * CVOL + (size_t)d * (VALID * VALID);
        #pragma unroll
        for (int hh = 0; hh < 3; ++hh) {
            if (hh < 2 || tall) {
                int h = 2 * hg + hh;
                Cn[h * VALID + 2 * wq + 1] = acc[hh][0];
                Cn[h * VALID + 2 * wq + 2] = acc[hh][1];
                if (w0t) Cn[h * VALID] = accw0[hh];
            }
        }
    }
}

// Blocks 0..863: one wave per active cell (n, i<3, j<3, k<3); lane = p1-subcell;
// fused nsplit reduction; butterfly sum. Blocks 864..988: constant fill.
__global__ __launch_bounds__(64) void pool_kernel(const float* __restrict__ C,
                                                  const float* __restrict__ wsB,
                                                  float* __restrict__ out,
                                                  int nsplit) {
    const int b = blockIdx.x;
    const int l = threadIdx.x;
    const float B = wsB[0];

    if (b < 864) {
        const int n = b / 27;
        const int cell = b - n * 27;
        const int ci = cell / 9, cj = (cell / 3) % 3, ck = cell % 3;
        float v = 0.f;
        if (l < 27) {
            const int da = l / 9, db = (l / 3) % 3, dc = l % 3;
            const int pz = 3 * ci + da, py = 3 * cj + db, px = 3 * ck + dc;
            const float* Cn = C + (size_t)n * CVOL;
            float m = -INFINITY;
            #pragma unroll
            for (int dz = 0; dz < 2; ++dz)
            #pragma unroll
            for (int dy = 0; dy < 2; ++dy)
            #pragma unroll
            for (int dx = 0; dx < 2; ++dx) {
                int z = 2 * pz + dz, y = 2 * py + dy, xx = 2 * px + dx;
                float t;
                if (z < VALID && y < VALID && xx < VALID) {
                    size_t off = ((size_t)z * VALID + y) * VALID + xx;
                    float sum = 0.f;
                    for (int ss = 0; ss < nsplit; ++ss)
                        sum += Cn[(size_t)ss * NB * CVOL + off];
                    t = sum + B;
                } else {
                    t = B;
                }
                m = fmaxf(m, t);
            }
            v = m;
        }
        #pragma unroll
        for (int off = 32; off > 0; off >>= 1) v += __shfl_xor(v, off, 64);
        if (l == 0) out[n * 1000 + ci * 100 + cj * 10 + ck] = v;
    } else {
        const int fb = b - 864;           // 0..124
        #pragma unroll
        for (int t = 0; t < 4; ++t) {
            int idx = fb * 256 + 64 * t + l;
            if (idx < 32000) {
                int r = idx % 1000;
                int i = r / 100, j = (r / 10) % 10, k = r % 10;
                if (i >= 3 || j >= 3 || k >= 3) out[idx] = 27.f * B;
            }
        }
    }
}

extern "C" void kernel_launch(void* const* d_in, const int* in_sizes, int n_in,
                              void* d_out, int out_size, void* d_ws, size_t ws_size,
                              hipStream_t stream) {
    const float* x      = (const float*)d_in[0];
    const float* weight = (const float*)d_in[1];
    const float* bias   = (const float*)d_in[2];
    float* out = (float*)d_out;
    float* ws  = (float*)d_ws;
    float* weff = ws;
    float* wsB  = ws + 4000;
    float* C    = ws + 4096;

    int nsplit = 1;
    if      (ws_size >= (size_t)(4096 + 8 * NB * CVOL) * 4) nsplit = 8;
    else if (ws_size >= (size_t)(4096 + 4 * NB * CVOL) * 4) nsplit = 4;
    else if (ws_size >= (size_t)(4096 + 2 * NB * CVOL) * 4) nsplit = 2;
    int cpS = CIN / nsplit;

    prep_kernel<<<dim3(16), dim3(256), 0, stream>>>(weight, bias, ws);
    conv_kernel<<<dim3(nsplit * NB * 9), dim3(128), 0, stream>>>(x, weff, C, cpS);
    pool_kernel<<<dim3(989), dim3(64), 0, stream>>>(C, wsB, out, nsplit);
}

// Round 19
// 91.839 us; speedup vs baseline: 1.0516x; 1.0516x over previous
//
#include <hip/hip_runtime.h>
#include <math.h>

#define NB 32
#define CIN 32
#define DIM 32
#define KK 5
#define VALID 17
#define CVOL (VALID*VALID*VALID)   // 4913
#define NSPL 8
#define CPS  4                     // cins per split

// bf16 LDS slab: 7 planes x [36 rows x 40 u16 (80B stride)] + 1 zero tail row.
// row = ih+2 (data rows 2..33); cols 32..39 permanent zero pad.
#define RSU 40
#define PRWS 36
#define PLNU (PRWS*RSU)            // 1440 u16
#define SLABU (7*PLNU + RSU)       // 10120 u16 -> pad to 10144 (20288 B) -> 7 blocks/CU

// ws layout (f32 words): [0,4000) w_eff ; [4000] B ; [4096, +409600) B-frag table (u16 hi/lo);
// C partials at word 413696: [NSPL][32][4913]
#define BT_WORD 4096
#define C_WORD  (4096 + 409600)

typedef __attribute__((ext_vector_type(8))) short short8;
typedef __attribute__((ext_vector_type(4))) float f32x4;

__device__ __forceinline__ unsigned short f2bf(float f) {   // RNE f32->bf16
    unsigned int u = __float_as_uint(f);
    u += 0x7FFFu + ((u >> 16) & 1u);
    return (unsigned short)(u >> 16);
}
__device__ __forceinline__ unsigned int pack2bf(float a, float b) {
    return (unsigned int)f2bf(a) | ((unsigned int)f2bf(b) << 16);
}
__device__ __forceinline__ float bflo(unsigned int u) { return __uint_as_float(u << 16); }
__device__ __forceinline__ float bfhi(unsigned int u) { return __uint_as_float(u & 0xFFFF0000u); }

__global__ __launch_bounds__(256) void prep_kernel(const float* __restrict__ weight,
                                                   const float* __restrict__ bias,
                                                   float* __restrict__ ws) {
    int idx = blockIdx.x * 256 + threadIdx.x;
    if (idx < 4000) {
        float s = 0.f;
        #pragma unroll 8
        for (int co = 0; co < 64; ++co) s += weight[co * 4000 + idx];
        ws[idx] = s;
    }
    if (idx == 0) {
        float b = 0.f;
        for (int i = 0; i < 64; ++i) b += bias[i];
        ws[4000] = b;
    }
}

// Build per-lane MFMA B-fragments for the banded matrix W~[k][w] = w5[k-2w+2].
// Layout: btbl u16 [slab=cin*25+kd*5+kh][hl 2][lane 64][e 8]. k = (lane>>4)*8+e, w = lane&15.
// hi = rne(v); lo = rne(v - f32(hi))  (Whi+Wlo split keeps weight error negligible).
__global__ __launch_bounds__(256) void prep2_kernel(const float* __restrict__ ws,
                                                    unsigned short* __restrict__ btbl) {
    int t = blockIdx.x * 256 + threadIdx.x;
    if (t >= 800 * 64) return;
    int slab = t >> 6, lane = t & 63;
    int w = lane & 15, q = lane >> 4;
    const float* w5 = ws + slab * 5;   // = weff + cin*125 + kd*25 + kh*5
    unsigned int hi[4], lo[4];
    #pragma unroll
    for (int pr = 0; pr < 4; ++pr) {
        float v0, v1; unsigned short h0, h1, l0, l1;
        int e0 = 2 * pr, e1 = 2 * pr + 1;
        int i0 = q * 8 + e0 - 2 * w + 2;
        int i1 = q * 8 + e1 - 2 * w + 2;
        v0 = (i0 >= 0 && i0 < 5) ? w5[i0] : 0.f;
        v1 = (i1 >= 0 && i1 < 5) ? w5[i1] : 0.f;
        h0 = f2bf(v0); l0 = f2bf(v0 - __uint_as_float((unsigned)h0 << 16));
        h1 = f2bf(v1); l1 = f2bf(v1 - __uint_as_float((unsigned)h1 << 16));
        hi[pr] = (unsigned)h0 | ((unsigned)h1 << 16);
        lo[pr] = (unsigned)l0 | ((unsigned)l1 << 16);
    }
    unsigned short* dst = btbl + (size_t)slab * 1024 + lane * 8;
    *(uint4*)dst         = make_uint4(hi[0], hi[1], hi[2], hi[3]);
    *(uint4*)(dst + 512) = make_uint4(lo[0], lo[1], lo[2], lo[3]);
}

// Block = (split s, n, d-pair p). 128 threads, 2 waves; wave dq handles d = 2p+dq.
// Interior 16x16 (h,w in 0..15) via 50 MFMAs/cin (25 taps x Whi/Wlo); edges (h=16 row,
// w=16 col incl corner) via exec-masked VALU using f32 weights. All per split -> pool unchanged.
__global__ __launch_bounds__(128) void conv_kernel(const float* __restrict__ x,
                                                   const float* __restrict__ weff,
                                                   const unsigned short* __restrict__ btbl,
                                                   float* __restrict__ C) {
    __shared__ __align__(16) unsigned short slab[10144];
    const int b = blockIdx.x;
    const int s = b / (NB * 9);
    const int rem = b - s * (NB * 9);
    const int n = rem / 9;
    const int p = rem - n * 9;
    const int tid = threadIdx.x;
    const int dq = tid >> 6;
    const int lane = tid & 63;
    const int hm = lane & 15;          // A row (h) for MFMA / D col (w) on output
    const int q8 = lane >> 4;          // k-quad
    const int d = 2 * p + dq;
    const bool dok = (d < VALID);

    // zero slab once (pads/OOB planes stay zero)
    for (int t = tid; t < 10144 / 8; t += 128) ((uint4*)slab)[t] = make_uint4(0u, 0u, 0u, 0u);
    __syncthreads();

    const int cin0 = s * CPS;
    const int r = tid >> 2;            // stage row 0..31
    const int q = tid & 3;             // stage quad (8-float chunk)

    f32x4 accH = {0.f, 0.f, 0.f, 0.f};
    f32x4 accL = {0.f, 0.f, 0.f, 0.f};
    float eC = 0.f, eR = 0.f;
    const bool colL = (lane < 17);           // w=16 column, h = lane
    const bool rowL = (lane >= 32 && lane < 48); // h=16 row, w = lane-32
    const int wr = lane - 32;

    for (int ci = 0; ci < CPS; ++ci) {
        const int cin = cin0 + ci;
        // ---- stage: f32 -> bf16 pack, ds_write_b128; chunk = plane c, row r, cols 8q..8q+7
        const float* xc = x + ((size_t)n * CIN + cin) * (DIM * DIM * DIM);
        #pragma unroll
        for (int c = 0; c < 7; ++c) {
            int id = 4 * p - 2 + c;
            if (id >= 0 && id < DIM) {             // block-uniform
                const float* src = xc + (size_t)id * 1024 + r * 32 + q * 8;
                float4 v0 = *(const float4*)src;
                float4 v1 = *(const float4*)(src + 4);
                uint4 u = make_uint4(pack2bf(v0.x, v0.y), pack2bf(v0.z, v0.w),
                                     pack2bf(v1.x, v1.y), pack2bf(v1.z, v1.w));
                *(uint4*)(slab + c * PLNU + (r + 2) * RSU + q * 8) = u;
            }
        }
        __syncthreads();

        // ---- interior: 25 (kd,kh) MFMAs x {hi,lo}
        const unsigned short* bt = btbl + (size_t)cin * 25 * 1024;
        #pragma unroll
        for (int kd = 0; kd < KK; ++kd) {
            const unsigned short* pl = slab + (2 * dq + kd) * PLNU;
            #pragma unroll
            for (int kh = 0; kh < KK; ++kh) {
                short8 A  = *(const short8*)(pl + (2 * hm + kh) * RSU + q8 * 8);
                short8 BH = *(const short8*)(bt + (kd * 5 + kh) * 1024 + lane * 8);
                short8 BL = *(const short8*)(bt + (kd * 5 + kh) * 1024 + 512 + lane * 8);
                accH = __builtin_amdgcn_mfma_f32_16x16x32_bf16(A, BH, accH, 0, 0, 0);
                accL = __builtin_amdgcn_mfma_f32_16x16x32_bf16(A, BL, accL, 0, 0, 0);
            }
        }

        // ---- edges (f32 weights; bf16 x from LDS)
        const float* wf = weff + cin * 125;
        if (colL) {   // out[h=lane][16]: taps iw 30,31 (kw 0,1); rows 2h+kh (zeros absorb OOB)
            #pragma unroll
            for (int kd = 0; kd < KK; ++kd) {
                const unsigned short* pl = slab + (2 * dq + kd) * PLNU;
                #pragma unroll
                for (int kh = 0; kh < KK; ++kh) {
                    unsigned v = *(const unsigned*)(pl + (2 * lane + kh) * RSU + 30);
                    eC = fmaf(wf[kd * 25 + kh * 5 + 0], bflo(v), eC);
                    eC = fmaf(wf[kd * 25 + kh * 5 + 1], bfhi(v), eC);
                }
            }
        }
        if (rowL) {   // out[16][w=wr]: rows 32+kh (kh 0,1 valid; others zero rows)
            const int off = (wr > 0) ? (2 * wr - 2) : 0;
            #pragma unroll
            for (int kd = 0; kd < KK; ++kd) {
                const unsigned short* pl = slab + (2 * dq + kd) * PLNU;
                #pragma unroll
                for (int kh = 0; kh < 2; ++kh) {
                    const unsigned short* rp = pl + (32 + kh) * RSU;
                    uint2 e4 = *(const uint2*)(rp + off);
                    unsigned f2 = *(const unsigned*)(rp + 2 * wr + 2);
                    float t0 = bflo(e4.x), t1 = bfhi(e4.x), t2 = bflo(e4.y), t3 = bfhi(e4.y);
                    float t4 = bflo(f2);
                    float k0 = wr ? t0 : 0.f, k1 = wr ? t1 : 0.f;
                    float k2 = wr ? t2 : t0,  k3 = wr ? t3 : t1,  k4 = wr ? t4 : t2;
                    eR = fmaf(wf[kd * 25 + kh * 5 + 0], k0, eR);
                    eR = fmaf(wf[kd * 25 + kh * 5 + 1], k1, eR);
                    eR = fmaf(wf[kd * 25 + kh * 5 + 2], k2, eR);
                    eR = fmaf(wf[kd * 25 + kh * 5 + 3], k3, eR);
                    eR = fmaf(wf[kd * 25 + kh * 5 + 4], k4, eR);
                }
            }
        }
        __syncthreads();   // WAR before next stage
    }

    if (dok) {
        float* Cn = C + ((size_t)s * NB + n) * CVOL + (size_t)d * (VALID * VALID);
        // D layout (verified m89): col = lane&15, row = (lane>>4)*4 + reg
        #pragma unroll
        for (int rr = 0; rr < 4; ++rr) {
            int h = q8 * 4 + rr;
            Cn[h * VALID + hm] = accH[rr] + accL[rr];
        }
        if (colL) Cn[lane * VALID + 16] = eC;
        if (rowL) Cn[16 * VALID + wr] = eR;
    }
}

// Blocks 0..863: one wave per active cell; fused split reduction; butterfly sum.
// Blocks 864..988: constant fill.
__global__ __launch_bounds__(64) void pool_kernel(const float* __restrict__ C,
                                                  const float* __restrict__ wsB,
                                                  float* __restrict__ out,
                                                  int nsplit) {
    const int b = blockIdx.x;
    const int l = threadIdx.x;
    const float B = wsB[0];

    if (b < 864) {
        const int n = b / 27;
        const int cell = b - n * 27;
        const int ci = cell / 9, cj = (cell / 3) % 3, ck = cell % 3;
        float v = 0.f;
        if (l < 27) {
            const int da = l / 9, db = (l / 3) % 3, dc = l % 3;
            const int pz = 3 * ci + da, py = 3 * cj + db, px = 3 * ck + dc;
            const float* Cn = C + (size_t)n * CVOL;
            float m = -INFINITY;
            #pragma unroll
            for (int dz = 0; dz < 2; ++dz)
            #pragma unroll
            for (int dy = 0; dy < 2; ++dy)
            #pragma unroll
            for (int dx = 0; dx < 2; ++dx) {
                int z = 2 * pz + dz, y = 2 * py + dy, xx = 2 * px + dx;
                float t;
                if (z < VALID && y < VALID && xx < VALID) {
                    size_t off = ((size_t)z * VALID + y) * VALID + xx;
                    float sum = 0.f;
                    for (int ss = 0; ss < nsplit; ++ss)
                        sum += Cn[(size_t)ss * NB * CVOL + off];
                    t = sum + B;
                } else {
                    t = B;
                }
                m = fmaxf(m, t);
            }
            v = m;
        }
        #pragma unroll
        for (int off = 32; off > 0; off >>= 1) v += __shfl_xor(v, off, 64);
        if (l == 0) out[n * 1000 + ci * 100 + cj * 10 + ck] = v;
    } else {
        const int fb = b - 864;
        #pragma unroll
        for (int t = 0; t < 4; ++t) {
            int idx = fb * 256 + 64 * t + l;
            if (idx < 32000) {
                int r = idx % 1000;
                int i = r / 100, j = (r / 10) % 10, k = r % 10;
                if (i >= 3 || j >= 3 || k >= 3) out[idx] = 27.f * B;
            }
        }
    }
}

extern "C" void kernel_launch(void* const* d_in, const int* in_sizes, int n_in,
                              void* d_out, int out_size, void* d_ws, size_t ws_size,
                              hipStream_t stream) {
    const float* x      = (const float*)d_in[0];
    const float* weight = (const float*)d_in[1];
    const float* bias   = (const float*)d_in[2];
    float* out = (float*)d_out;
    float* ws  = (float*)d_ws;
    float* weff = ws;
    float* wsB  = ws + 4000;
    unsigned short* btbl = (unsigned short*)(ws + BT_WORD);
    float* C = ws + C_WORD;

    prep_kernel<<<dim3(16), dim3(256), 0, stream>>>(weight, bias, ws);
    prep2_kernel<<<dim3(200), dim3(256), 0, stream>>>(ws, btbl);
    conv_kernel<<<dim3(NSPL * NB * 9), dim3(128), 0, stream>>>(x, weff, btbl, C);
    pool_kernel<<<dim3(989), dim3(64), 0, stream>>>(C, wsB, out, NSPL);
}

// Round 20
// 80.853 us; speedup vs baseline: 1.1944x; 1.1359x over previous
//
#include <hip/hip_runtime.h>
#include <math.h>

#define NB 32
#define CIN 32
#define DIM 32
#define KK 5
#define VALID 17
#define CVOL (VALID*VALID*VALID)   // 4913
#define PW 1024                    // plane words (32*32), linear
#define SLABF (7*PW + 4)           // 28688 B -> 5 blocks/CU (with 256 threads = 20 waves/CU)

// ws layout (floats): [0,4000) w_eff ; [4000] B ; [4096, ...) C partials [nsplit][32][4913]

__global__ __launch_bounds__(256) void prep_kernel(const float* __restrict__ weight,
                                                   const float* __restrict__ bias,
                                                   float* __restrict__ ws) {
    int idx = blockIdx.x * 256 + threadIdx.x;
    if (idx < 4000) {
        float s = 0.f;
        #pragma unroll 8
        for (int co = 0; co < 64; ++co) s += weight[co * 4000 + idx];
        ws[idx] = s;
    }
    if (idx == 0) {
        float b = 0.f;
        for (int i = 0; i < 64; ++i) b += bias[i];
        ws[4000] = b;
    }
}

__device__ __forceinline__ void gload_lds16(const float* g, float* l) {
    __builtin_amdgcn_global_load_lds((const __attribute__((address_space(1))) void*)g,
                                     (__attribute__((address_space(3))) void*)l,
                                     16, 0, 0);
}

// shfl_down-by-1 (lane i <- i+1) via row_shl:1 — verified r16 (absmax 0).
// MUST be unconditional-in-straight-line or within a region where the source lane's
// predicate matches the dest's (r17 convergence bug: ternary-wrapped DPP lost lane 6 taps).
__device__ __forceinline__ float dpp_shl1(float v) {
    return __int_as_float(__builtin_amdgcn_update_dpp(0, __float_as_int(v),
                                                      0x101 /*row_shl:1*/, 0xF, 0xF, true));
}

// Block = (split s, n, d-pair p), 256 threads = 4 waves.
// wv = tid>>6: dq = wv>>1 (d = 2p+dq), hb = wv&1 (h-half). lane: hg = lane>>3, wq = lane&7.
// Wave hb=0: output row h = hg (rows 0..7) + [hg7: also h=16 tail, kh 0,1 only].
// Wave hb=1: output row h = 8+hg (rows 8..15).
// Per thread: w = 2wq+1, 2wq+2 (+ w=0 via accw0 for wq0). One output row -> 25 guarded
// ds_read_b128 + DPP vb per cin. Same r12 slab/staging; 2x waves/CU vs r12 (the lever).
// NOTE: no min-waves launch-bound arg (r10: (N,4) forced spill, 6x). Staging wave-uniform 1KB.
__global__ __launch_bounds__(256) void conv_kernel(const float* __restrict__ x,
                                                   const float* __restrict__ weff,
                                                   float* __restrict__ C,
                                                   int cpS) {
    __shared__ __align__(16) float slab[SLABF];
    const int b = blockIdx.x;
    const int s = b / (NB * 9);
    const int rem = b - s * (NB * 9);
    const int n = rem / 9;
    const int p = rem - n * 9;
    const int tid = threadIdx.x;
    const int wv = tid >> 6;
    const int dq = wv >> 1;
    const int hb = wv & 1;
    const int lane = tid & 63;
    const int hg = lane >> 3;
    const int wq = lane & 7;
    const int d = 2 * p + dq;
    const bool dok = (d < VALID);
    const int h = hb ? (8 + hg) : hg;
    const bool tall = (hb == 0) && (hg == 7);   // wave A hg7 also does h=16
    const bool w7ok = (wq < 7);
    const bool w0t  = (wq == 0);

    // zero slab once: OOB planes (never staged) must read as 0
    for (int t = tid; t < SLABF / 4; t += 256) ((float4*)slab)[t] = make_float4(0.f, 0.f, 0.f, 0.f);
    __syncthreads();

    const int id0 = 4 * p - 2;
    const int cin0 = s * cpS;

    float acc0 = 0.f, acc1 = 0.f, aw0 = 0.f;
    float accT0 = 0.f, accT1 = 0.f, awT = 0.f;

    for (int ci = 0; ci < cpS; ++ci) {
        // stage: 28 slots (7 planes x 4 x 1KB); wave wv issues slots [7wv, 7wv+7)
        const float* xc = x + ((size_t)n * CIN + (cin0 + ci)) * (DIM * DIM * DIM);
        #pragma unroll
        for (int st = 0; st < 7; ++st) {
            int slot = wv * 7 + st;           // wave-uniform
            int pi = slot >> 2, c = slot & 3;
            int id = id0 + pi;
            if (id >= 0 && id < DIM) {        // wave-uniform guard
                gload_lds16(xc + (size_t)id * PW + c * 256 + lane * 4,
                            slab + pi * PW + c * 256);
            }
        }
        __syncthreads();   // staged data visible

        const float* wb = weff + (cin0 + ci) * 125;
        #pragma unroll
        for (int kd = 0; kd < KK; ++kd) {
            const float* plane = slab + (2 * dq + kd) * PW;
            #pragma unroll
            for (int kh = 0; kh < KK; ++kh) {
                const int ih = 2 * h - 2 + kh;
                if ((unsigned)ih < 32u) {      // hg-uniform predicate
                    const float4 va = *(const float4*)(plane + ih * 32 + 4 * wq);
                    const float t0 = dpp_shl1(va.x);
                    const float t1 = dpp_shl1(va.y);
                    const float t2 = dpp_shl1(va.z);
                    const float vb0 = w7ok ? t0 : 0.f;
                    const float vb1 = w7ok ? t1 : 0.f;
                    const float vb2 = w7ok ? t2 : 0.f;
                    const float w0 = wb[kd * 25 + kh * 5 + 0];
                    const float w1 = wb[kd * 25 + kh * 5 + 1];
                    const float w2 = wb[kd * 25 + kh * 5 + 2];
                    const float w3 = wb[kd * 25 + kh * 5 + 3];
                    const float w4 = wb[kd * 25 + kh * 5 + 4];
                    acc0 = fmaf(w0, va.x, acc0);
                    acc1 = fmaf(w0, va.z, acc1);
                    acc0 = fmaf(w1, va.y, acc0);
                    acc1 = fmaf(w1, va.w, acc1);
                    acc0 = fmaf(w2, va.z, acc0);
                    acc1 = fmaf(w2, vb0, acc1);
                    acc0 = fmaf(w3, va.w, acc0);
                    acc1 = fmaf(w3, vb1, acc1);
                    acc0 = fmaf(w4, vb0, acc0);
                    acc1 = fmaf(w4, vb2, acc1);
                    aw0  = fmaf(w2, va.x, aw0);
                    aw0  = fmaf(w3, va.y, aw0);
                    aw0  = fmaf(w4, va.z, aw0);
                }
            }
            if (tall) {   // h=16: ih = 30+kh valid only for kh 0,1 (group-uniform predicate)
                #pragma unroll
                for (int kh = 0; kh < 2; ++kh) {
                    const float4 va = *(const float4*)(plane + (30 + kh) * 32 + 4 * wq);
                    const float t0 = dpp_shl1(va.x);
                    const float t1 = dpp_shl1(va.y);
                    const float t2 = dpp_shl1(va.z);
                    const float vb0 = w7ok ? t0 : 0.f;
                    const float vb1 = w7ok ? t1 : 0.f;
                    const float vb2 = w7ok ? t2 : 0.f;
                    const float w0 = wb[kd * 25 + kh * 5 + 0];
                    const float w1 = wb[kd * 25 + kh * 5 + 1];
                    const float w2 = wb[kd * 25 + kh * 5 + 2];
                    const float w3 = wb[kd * 25 + kh * 5 + 3];
                    const float w4 = wb[kd * 25 + kh * 5 + 4];
                    accT0 = fmaf(w0, va.x, accT0);
                    accT1 = fmaf(w0, va.z, accT1);
                    accT0 = fmaf(w1, va.y, accT0);
                    accT1 = fmaf(w1, va.w, accT1);
                    accT0 = fmaf(w2, va.z, accT0);
                    accT1 = fmaf(w2, vb0, accT1);
                    accT0 = fmaf(w3, va.w, accT0);
                    accT1 = fmaf(w3, vb1, accT1);
                    accT0 = fmaf(w4, vb0, accT0);
                    accT1 = fmaf(w4, vb2, accT1);
                    awT   = fmaf(w2, va.x, awT);
                    awT   = fmaf(w3, va.y, awT);
                    awT   = fmaf(w4, va.z, awT);
                }
            }
        }
        __syncthreads();   // WAR: next stage overwrites slab
    }

    if (dok) {
        float* Cn = C + ((size_t)s * NB + n) * CVOL + (size_t)d * (VALID * VALID);
        Cn[h * VALID + 2 * wq + 1] = acc0;
        Cn[h * VALID + 2 * wq + 2] = acc1;
        if (w0t) Cn[h * VALID] = aw0;
        if (tall) {
            Cn[16 * VALID + 2 * wq + 1] = accT0;
            Cn[16 * VALID + 2 * wq + 2] = accT1;
            if (w0t) Cn[16 * VALID] = awT;
        }
    }
}

// Blocks 0..863: one wave per active cell (n, i<3, j<3, k<3); lane = p1-subcell;
// fused nsplit reduction; butterfly sum. Blocks 864..988: constant fill.
__global__ __launch_bounds__(64) void pool_kernel(const float* __restrict__ C,
                                                  const float* __restrict__ wsB,
                                                  float* __restrict__ out,
                                                  int nsplit) {
    const int b = blockIdx.x;
    const int l = threadIdx.x;
    const float B = wsB[0];

    if (b < 864) {
        const int n = b / 27;
        const int cell = b - n * 27;
        const int ci = cell / 9, cj = (cell / 3) % 3, ck = cell % 3;
        float v = 0.f;
        if (l < 27) {
            const int da = l / 9, db = (l / 3) % 3, dc = l % 3;
            const int pz = 3 * ci + da, py = 3 * cj + db, px = 3 * ck + dc;
            const float* Cn = C + (size_t)n * CVOL;
            float m = -INFINITY;
            #pragma unroll
            for (int dz = 0; dz < 2; ++dz)
            #pragma unroll
            for (int dy = 0; dy < 2; ++dy)
            #pragma unroll
            for (int dx = 0; dx < 2; ++dx) {
                int z = 2 * pz + dz, y = 2 * py + dy, xx = 2 * px + dx;
                float t;
                if (z < VALID && y < VALID && xx < VALID) {
                    size_t off = ((size_t)z * VALID + y) * VALID + xx;
                    float sum = 0.f;
                    for (int ss = 0; ss < nsplit; ++ss)
                        sum += Cn[(size_t)ss * NB * CVOL + off];
                    t = sum + B;
                } else {
                    t = B;
                }
                m = fmaxf(m, t);
            }
            v = m;
        }
        #pragma unroll
        for (int off = 32; off > 0; off >>= 1) v += __shfl_xor(v, off, 64);
        if (l == 0) out[n * 1000 + ci * 100 + cj * 10 + ck] = v;
    } else {
        const int fb = b - 864;           // 0..124
        #pragma unroll
        for (int t = 0; t < 4; ++t) {
            int idx = fb * 256 + 64 * t + l;
            if (idx < 32000) {
                int r = idx % 1000;
                int i = r / 100, j = (r / 10) % 10, k = r % 10;
                if (i >= 3 || j >= 3 || k >= 3) out[idx] = 27.f * B;
            }
        }
    }
}

extern "C" void kernel_launch(void* const* d_in, const int* in_sizes, int n_in,
                              void* d_out, int out_size, void* d_ws, size_t ws_size,
                              hipStream_t stream) {
    const float* x      = (const float*)d_in[0];
    const float* weight = (const float*)d_in[1];
    const float* bias   = (const float*)d_in[2];
    float* out = (float*)d_out;
    float* ws  = (float*)d_ws;
    float* weff = ws;
    float* wsB  = ws + 4000;
    float* C    = ws + 4096;

    int nsplit = 1;
    if      (ws_size >= (size_t)(4096 + 8 * NB * CVOL) * 4) nsplit = 8;
    else if (ws_size >= (size_t)(4096 + 4 * NB * CVOL) * 4) nsplit = 4;
    else if (ws_size >= (size_t)(4096 + 2 * NB * CVOL) * 4) nsplit = 2;
    int cpS = CIN / nsplit;

    prep_kernel<<<dim3(16), dim3(256), 0, stream>>>(weight, bias, ws);
    conv_kernel<<<dim3(nsplit * NB * 9), dim3(256), 0, stream>>>(x, weff, C, cpS);
    pool_kernel<<<dim3(989), dim3(64), 0, stream>>>(C, wsB, out, nsplit);
}

// Round 21
// 77.882 us; speedup vs baseline: 1.2400x; 1.0382x over previous
//
#include <hip/hip_runtime.h>
#include <math.h>

#define NB 32
#define CIN 32
#define DIM 32
#define KK 5
#define VALID 17
#define CVOL (VALID*VALID*VALID)   // 4913
#define PW 1024                    // plane words (32*32), linear
#define SLABF (7*PW + 4)           // 28688 B -> 5 blocks/CU (256 threads = 20 waves/CU)

// ws layout (floats): [0,4000) w_eff ; [4000] B ; [4096, ...) C partials [nsplit][32][4913]

__global__ __launch_bounds__(256) void prep_kernel(const float* __restrict__ weight,
                                                   const float* __restrict__ bias,
                                                   float* __restrict__ ws) {
    int idx = blockIdx.x * 256 + threadIdx.x;
    if (idx < 4000) {
        float s = 0.f;
        #pragma unroll 8
        for (int co = 0; co < 64; ++co) s += weight[co * 4000 + idx];
        ws[idx] = s;
    }
    if (idx == 0) {
        float b = 0.f;
        for (int i = 0; i < 64; ++i) b += bias[i];
        ws[4000] = b;
    }
}

__device__ __forceinline__ void gload_lds16(const float* g, float* l) {
    __builtin_amdgcn_global_load_lds((const __attribute__((address_space(1))) void*)g,
                                     (__attribute__((address_space(3))) void*)l,
                                     16, 0, 0);
}

// shfl_down-by-1 (lane i <- i+1) via row_shl:1 — verified r16 (absmax 0).
// MUST be unconditional-in-straight-line (r17 convergence bug: ternary-wrapped DPP
// exec-masked the source lane -> lane 6 lost taps).
__device__ __forceinline__ float dpp_shl1(float v) {
    return __int_as_float(__builtin_amdgcn_update_dpp(0, __float_as_int(v),
                                                      0x101 /*row_shl:1*/, 0xF, 0xF, true));
}

// Block = (split s, n, d-pair p), 256 threads = 4 waves.
// wv = tid>>6: dq = wv>>1 (d = 2p+dq), hb = wv&1 (h-half). lane: hg = lane>>3, wq = lane&7.
// Wave hb=0: h = hg (0..7) + [hg7: also h=16 tail, kh 0,1]. Wave hb=1: h = 8+hg (8..15).
// Per thread: w = 2wq+1, 2wq+2 (+ w=0 via accw0 for wq0). 25 guarded ds_read_b128 + DPP
// vb per cin. r12 slab/staging; nsplit=4 (cpS=8): prologue amortized 2x, grid fully
// co-resident (1152 blocks <= 1280 residency), pool chain halved.
// NOTE: no min-waves launch-bound arg (r10: (N,4) forced spill, 6x). Staging wave-uniform 1KB.
__global__ __launch_bounds__(256) void conv_kernel(const float* __restrict__ x,
                                                   const float* __restrict__ weff,
                                                   float* __restrict__ C,
                                                   int cpS) {
    __shared__ __align__(16) float slab[SLABF];
    const int b = blockIdx.x;
    const int s = b / (NB * 9);
    const int rem = b - s * (NB * 9);
    const int n = rem / 9;
    const int p = rem - n * 9;
    const int tid = threadIdx.x;
    const int wv = tid >> 6;
    const int dq = wv >> 1;
    const int hb = wv & 1;
    const int lane = tid & 63;
    const int hg = lane >> 3;
    const int wq = lane & 7;
    const int d = 2 * p + dq;
    const bool dok = (d < VALID);
    const int h = hb ? (8 + hg) : hg;
    const bool tall = (hb == 0) && (hg == 7);   // wave A hg7 also does h=16
    const bool w7ok = (wq < 7);
    const bool w0t  = (wq == 0);

    // zero slab once: OOB planes (never staged) must read as 0
    for (int t = tid; t < SLABF / 4; t += 256) ((float4*)slab)[t] = make_float4(0.f, 0.f, 0.f, 0.f);
    __syncthreads();

    const int id0 = 4 * p - 2;
    const int cin0 = s * cpS;

    float acc0 = 0.f, acc1 = 0.f, aw0 = 0.f;
    float accT0 = 0.f, accT1 = 0.f, awT = 0.f;

    for (int ci = 0; ci < cpS; ++ci) {
        // stage: 28 slots (7 planes x 4 x 1KB); wave wv issues slots [7wv, 7wv+7)
        const float* xc = x + ((size_t)n * CIN + (cin0 + ci)) * (DIM * DIM * DIM);
        #pragma unroll
        for (int st = 0; st < 7; ++st) {
            int slot = wv * 7 + st;           // wave-uniform
            int pi = slot >> 2, c = slot & 3;
            int id = id0 + pi;
            if (id >= 0 && id < DIM) {        // wave-uniform guard
                gload_lds16(xc + (size_t)id * PW + c * 256 + lane * 4,
                            slab + pi * PW + c * 256);
            }
        }
        __syncthreads();   // staged data visible

        const float* wb = weff + (cin0 + ci) * 125;
        #pragma unroll
        for (int kd = 0; kd < KK; ++kd) {
            const float* plane = slab + (2 * dq + kd) * PW;
            #pragma unroll
            for (int kh = 0; kh < KK; ++kh) {
                const int ih = 2 * h - 2 + kh;
                if ((unsigned)ih < 32u) {      // hg-uniform predicate
                    const float4 va = *(const float4*)(plane + ih * 32 + 4 * wq);
                    const float t0 = dpp_shl1(va.x);
                    const float t1 = dpp_shl1(va.y);
                    const float t2 = dpp_shl1(va.z);
                    const float vb0 = w7ok ? t0 : 0.f;
                    const float vb1 = w7ok ? t1 : 0.f;
                    const float vb2 = w7ok ? t2 : 0.f;
                    const float w0 = wb[kd * 25 + kh * 5 + 0];
                    const float w1 = wb[kd * 25 + kh * 5 + 1];
                    const float w2 = wb[kd * 25 + kh * 5 + 2];
                    const float w3 = wb[kd * 25 + kh * 5 + 3];
                    const float w4 = wb[kd * 25 + kh * 5 + 4];
                    acc0 = fmaf(w0, va.x, acc0);
                    acc1 = fmaf(w0, va.z, acc1);
                    acc0 = fmaf(w1, va.y, acc0);
                    acc1 = fmaf(w1, va.w, acc1);
                    acc0 = fmaf(w2, va.z, acc0);
                    acc1 = fmaf(w2, vb0, acc1);
                    acc0 = fmaf(w3, va.w, acc0);
                    acc1 = fmaf(w3, vb1, acc1);
                    acc0 = fmaf(w4, vb0, acc0);
                    acc1 = fmaf(w4, vb2, acc1);
                    aw0  = fmaf(w2, va.x, aw0);
                    aw0  = fmaf(w3, va.y, aw0);
                    aw0  = fmaf(w4, va.z, aw0);
                }
            }
            if (tall) {   // h=16: ih = 30+kh valid only for kh 0,1 (group-uniform predicate)
                #pragma unroll
                for (int kh = 0; kh < 2; ++kh) {
                    const float4 va = *(const float4*)(plane + (30 + kh) * 32 + 4 * wq);
                    const float t0 = dpp_shl1(va.x);
                    const float t1 = dpp_shl1(va.y);
                    const float t2 = dpp_shl1(va.z);
                    const float vb0 = w7ok ? t0 : 0.f;
                    const float vb1 = w7ok ? t1 : 0.f;
                    const float vb2 = w7ok ? t2 : 0.f;
                    const float w0 = wb[kd * 25 + kh * 5 + 0];
                    const float w1 = wb[kd * 25 + kh * 5 + 1];
                    const float w2 = wb[kd * 25 + kh * 5 + 2];
                    const float w3 = wb[kd * 25 + kh * 5 + 3];
                    const float w4 = wb[kd * 25 + kh * 5 + 4];
                    accT0 = fmaf(w0, va.x, accT0);
                    accT1 = fmaf(w0, va.z, accT1);
                    accT0 = fmaf(w1, va.y, accT0);
                    accT1 = fmaf(w1, va.w, accT1);
                    accT0 = fmaf(w2, va.z, accT0);
                    accT1 = fmaf(w2, vb0, accT1);
                    accT0 = fmaf(w3, va.w, accT0);
                    accT1 = fmaf(w3, vb1, accT1);
                    accT0 = fmaf(w4, vb0, accT0);
                    accT1 = fmaf(w4, vb2, accT1);
                    awT   = fmaf(w2, va.x, awT);
                    awT   = fmaf(w3, va.y, awT);
                    awT   = fmaf(w4, va.z, awT);
                }
            }
        }
        __syncthreads();   // WAR: next stage overwrites slab
    }

    if (dok) {
        float* Cn = C + ((size_t)s * NB + n) * CVOL + (size_t)d * (VALID * VALID);
        Cn[h * VALID + 2 * wq + 1] = acc0;
        Cn[h * VALID + 2 * wq + 2] = acc1;
        if (w0t) Cn[h * VALID] = aw0;
        if (tall) {
            Cn[16 * VALID + 2 * wq + 1] = accT0;
            Cn[16 * VALID + 2 * wq + 2] = accT1;
            if (w0t) Cn[16 * VALID] = awT;
        }
    }
}

// Blocks 0..863: one wave per active cell (n, i<3, j<3, k<3); lane = p1-subcell;
// fused nsplit reduction; butterfly sum. Blocks 864..988: constant fill.
__global__ __launch_bounds__(64) void pool_kernel(const float* __restrict__ C,
                                                  const float* __restrict__ wsB,
                                                  float* __restrict__ out,
                                                  int nsplit) {
    const int b = blockIdx.x;
    const int l = threadIdx.x;
    const float B = wsB[0];

    if (b < 864) {
        const int n = b / 27;
        const int cell = b - n * 27;
        const int ci = cell / 9, cj = (cell / 3) % 3, ck = cell % 3;
        float v = 0.f;
        if (l < 27) {
            const int da = l / 9, db = (l / 3) % 3, dc = l % 3;
            const int pz = 3 * ci + da, py = 3 * cj + db, px = 3 * ck + dc;
            const float* Cn = C + (size_t)n * CVOL;
            float m = -INFINITY;
            #pragma unroll
            for (int dz = 0; dz < 2; ++dz)
            #pragma unroll
            for (int dy = 0; dy < 2; ++dy)
            #pragma unroll
            for (int dx = 0; dx < 2; ++dx) {
                int z = 2 * pz + dz, y = 2 * py + dy, xx = 2 * px + dx;
                float t;
                if (z < VALID && y < VALID && xx < VALID) {
                    size_t off = ((size_t)z * VALID + y) * VALID + xx;
                    float sum = 0.f;
                    for (int ss = 0; ss < nsplit; ++ss)
                        sum += Cn[(size_t)ss * NB * CVOL + off];
                    t = sum + B;
                } else {
                    t = B;
                }
                m = fmaxf(m, t);
            }
            v = m;
        }
        #pragma unroll
        for (int off = 32; off > 0; off >>= 1) v += __shfl_xor(v, off, 64);
        if (l == 0) out[n * 1000 + ci * 100 + cj * 10 + ck] = v;
    } else {
        const int fb = b - 864;           // 0..124
        #pragma unroll
        for (int t = 0; t < 4; ++t) {
            int idx = fb * 256 + 64 * t + l;
            if (idx < 32000) {
                int r = idx % 1000;
                int i = r / 100, j = (r / 10) % 10, k = r % 10;
                if (i >= 3 || j >= 3 || k >= 3) out[idx] = 27.f * B;
            }
        }
    }
}

extern "C" void kernel_launch(void* const* d_in, const int* in_sizes, int n_in,
                              void* d_out, int out_size, void* d_ws, size_t ws_size,
                              hipStream_t stream) {
    const float* x      = (const float*)d_in[0];
    const float* weight = (const float*)d_in[1];
    const float* bias   = (const float*)d_in[2];
    float* out = (float*)d_out;
    float* ws  = (float*)d_ws;
    float* weff = ws;
    float* wsB  = ws + 4000;
    float* C    = ws + 4096;

    // nsplit=4 preferred: cpS=8 amortizes per-block prologue 2x; 1152 blocks fit in one
    // residency generation (5 blocks/CU x 256 = 1280); pool serial chain halves.
    int nsplit = 1;
    if      (ws_size >= (size_t)(4096 + 4 * NB * CVOL) * 4) nsplit = 4;
    else if (ws_size >= (size_t)(4096 + 2 * NB * CVOL) * 4) nsplit = 2;
    int cpS = CIN / nsplit;

    prep_kernel<<<dim3(16), dim3(256), 0, stream>>>(weight, bias, ws);
    conv_kernel<<<dim3(nsplit * NB * 9), dim3(256), 0, stream>>>(x, weff, C, cpS);
    pool_kernel<<<dim3(989), dim3(64), 0, stream>>>(C, wsB, out, nsplit);
}

// Round 22
// 73.987 us; speedup vs baseline: 1.3053x; 1.0526x over previous
//
#include <hip/hip_runtime.h>
#include <math.h>

#define NB 32
#define CIN 32
#define DIM 32
#define KK 5
#define VALID 17
#define CVOL (VALID*VALID*VALID)   // 4913
#define PW 1024                    // plane words (32*32), linear
#define PLN 9                      // planes for a d-triple: ids 6p-2 .. 6p+6
#define SLABF (PLN*PW + 4)         // 36880 B -> 4 blocks/CU (384 thr = 24 waves/CU)

// ws layout (floats): [0,4000) w_eff ; [4000] B ; [4096, ...) C partials [nsplit][32][4913]

__global__ __launch_bounds__(256) void prep_kernel(const float* __restrict__ weight,
                                                   const float* __restrict__ bias,
                                                   float* __restrict__ ws) {
    int idx = blockIdx.x * 256 + threadIdx.x;
    if (idx < 4000) {
        float s = 0.f;
        #pragma unroll 8
        for (int co = 0; co < 64; ++co) s += weight[co * 4000 + idx];
        ws[idx] = s;
    }
    if (idx == 0) {
        float b = 0.f;
        for (int i = 0; i < 64; ++i) b += bias[i];
        ws[4000] = b;
    }
}

__device__ __forceinline__ void gload_lds16(const float* g, float* l) {
    __builtin_amdgcn_global_load_lds((const __attribute__((address_space(1))) void*)g,
                                     (__attribute__((address_space(3))) void*)l,
                                     16, 0, 0);
}

// shfl_down-by-1 (lane i <- i+1) via row_shl:1 — verified r16 (absmax 0).
// MUST be unconditional-in-straight-line (r17 convergence bug: ternary-wrapped DPP
// exec-masked the source lane -> lane 6 lost taps).
__device__ __forceinline__ float dpp_shl1(float v) {
    return __int_as_float(__builtin_amdgcn_update_dpp(0, __float_as_int(v),
                                                      0x101 /*row_shl:1*/, 0xF, 0xF, true));
}

// Block = (split s, n, d-TRIPLE p), 384 threads = 6 waves.
// wv = tid>>6: dq = wv>>1 in {0,1,2} (d = 3p+dq), hb = wv&1. lane: hg = lane>>3, wq = lane&7.
// Wave hb=0: h = hg (0..7) + [hg7: h=16 tail, kh 0,1]. Wave hb=1: h = 8+hg.
// Slab: 9 linear planes, pi = id-(6p-2); kd plane of d: pi = 2dq+kd (identity 2d-2+kd = 6p-2+pi).
// vs r20/21: 24 waves/CU cap (was 20), staging 3 planes/d (was 3.5), grid 768 co-resident.
// NOTE: no min-waves launch-bound arg (r10 spill, 6x). Staging wave-uniform 1KB slots.
__global__ __launch_bounds__(384) void conv_kernel(const float* __restrict__ x,
                                                   const float* __restrict__ weff,
                                                   float* __restrict__ C,
                                                   int cpS) {
    __shared__ __align__(16) float slab[SLABF];
    const int b = blockIdx.x;
    const int s = b / (NB * 6);
    const int rem = b - s * (NB * 6);
    const int n = rem / 6;
    const int p = rem - n * 6;
    const int tid = threadIdx.x;
    const int wv = tid >> 6;
    const int dq = wv >> 1;
    const int hb = wv & 1;
    const int lane = tid & 63;
    const int hg = lane >> 3;
    const int wq = lane & 7;
    const int d = 3 * p + dq;
    const bool dok = (d < VALID);
    const int h = hb ? (8 + hg) : hg;
    const bool tall = (hb == 0) && (hg == 7);   // even waves' hg7 also do h=16
    const bool w7ok = (wq < 7);
    const bool w0t  = (wq == 0);

    // zero slab once: OOB planes (never staged) must read as 0
    for (int t = tid; t < SLABF / 4; t += 384) ((float4*)slab)[t] = make_float4(0.f, 0.f, 0.f, 0.f);
    __syncthreads();

    const int id0 = 6 * p - 2;
    const int cin0 = s * cpS;

    float acc0 = 0.f, acc1 = 0.f, aw0 = 0.f;
    float accT0 = 0.f, accT1 = 0.f, awT = 0.f;

    for (int ci = 0; ci < cpS; ++ci) {
        // stage: 36 slots (9 planes x 4 x 1KB); wave wv issues slots [6wv, 6wv+6)
        const float* xc = x + ((size_t)n * CIN + (cin0 + ci)) * (DIM * DIM * DIM);
        #pragma unroll
        for (int st = 0; st < 6; ++st) {
            int slot = wv * 6 + st;           // wave-uniform
            int pi = slot >> 2, c = slot & 3;
            int id = id0 + pi;
            if (id >= 0 && id < DIM) {        // wave-uniform guard
                gload_lds16(xc + (size_t)id * PW + c * 256 + lane * 4,
                            slab + pi * PW + c * 256);
            }
        }
        __syncthreads();   // staged data visible

        const float* wb = weff + (cin0 + ci) * 125;
        #pragma unroll
        for (int kd = 0; kd < KK; ++kd) {
            const float* plane = slab + (2 * dq + kd) * PW;
            #pragma unroll
            for (int kh = 0; kh < KK; ++kh) {
                const int ih = 2 * h - 2 + kh;
                if ((unsigned)ih < 32u) {      // hg-uniform predicate
                    const float4 va = *(const float4*)(plane + ih * 32 + 4 * wq);
                    const float t0 = dpp_shl1(va.x);
                    const float t1 = dpp_shl1(va.y);
                    const float t2 = dpp_shl1(va.z);
                    const float vb0 = w7ok ? t0 : 0.f;
                    const float vb1 = w7ok ? t1 : 0.f;
                    const float vb2 = w7ok ? t2 : 0.f;
                    const float w0 = wb[kd * 25 + kh * 5 + 0];
                    const float w1 = wb[kd * 25 + kh * 5 + 1];
                    const float w2 = wb[kd * 25 + kh * 5 + 2];
                    const float w3 = wb[kd * 25 + kh * 5 + 3];
                    const float w4 = wb[kd * 25 + kh * 5 + 4];
                    acc0 = fmaf(w0, va.x, acc0);
                    acc1 = fmaf(w0, va.z, acc1);
                    acc0 = fmaf(w1, va.y, acc0);
                    acc1 = fmaf(w1, va.w, acc1);
                    acc0 = fmaf(w2, va.z, acc0);
                    acc1 = fmaf(w2, vb0, acc1);
                    acc0 = fmaf(w3, va.w, acc0);
                    acc1 = fmaf(w3, vb1, acc1);
                    acc0 = fmaf(w4, vb0, acc0);
                    acc1 = fmaf(w4, vb2, acc1);
                    aw0  = fmaf(w2, va.x, aw0);
                    aw0  = fmaf(w3, va.y, aw0);
                    aw0  = fmaf(w4, va.z, aw0);
                }
            }
            if (tall) {   // h=16: ih = 30+kh valid only for kh 0,1 (group-uniform predicate)
                #pragma unroll
                for (int kh = 0; kh < 2; ++kh) {
                    const float4 va = *(const float4*)(plane + (30 + kh) * 32 + 4 * wq);
                    const float t0 = dpp_shl1(va.x);
                    const float t1 = dpp_shl1(va.y);
                    const float t2 = dpp_shl1(va.z);
                    const float vb0 = w7ok ? t0 : 0.f;
                    const float vb1 = w7ok ? t1 : 0.f;
                    const float vb2 = w7ok ? t2 : 0.f;
                    const float w0 = wb[kd * 25 + kh * 5 + 0];
                    const float w1 = wb[kd * 25 + kh * 5 + 1];
                    const float w2 = wb[kd * 25 + kh * 5 + 2];
                    const float w3 = wb[kd * 25 + kh * 5 + 3];
                    const float w4 = wb[kd * 25 + kh * 5 + 4];
                    accT0 = fmaf(w0, va.x, accT0);
                    accT1 = fmaf(w0, va.z, accT1);
                    accT0 = fmaf(w1, va.y, accT0);
                    accT1 = fmaf(w1, va.w, accT1);
                    accT0 = fmaf(w2, va.z, accT0);
                    accT1 = fmaf(w2, vb0, accT1);
                    accT0 = fmaf(w3, va.w, accT0);
                    accT1 = fmaf(w3, vb1, accT1);
                    accT0 = fmaf(w4, vb0, accT0);
                    accT1 = fmaf(w4, vb2, accT1);
                    awT   = fmaf(w2, va.x, awT);
                    awT   = fmaf(w3, va.y, awT);
                    awT   = fmaf(w4, va.z, awT);
                }
            }
        }
        __syncthreads();   // WAR: next stage overwrites slab
    }

    if (dok) {
        float* Cn = C + ((size_t)s * NB + n) * CVOL + (size_t)d * (VALID * VALID);
        Cn[h * VALID + 2 * wq + 1] = acc0;
        Cn[h * VALID + 2 * wq + 2] = acc1;
        if (w0t) Cn[h * VALID] = aw0;
        if (tall) {
            Cn[16 * VALID + 2 * wq + 1] = accT0;
            Cn[16 * VALID + 2 * wq + 2] = accT1;
            if (w0t) Cn[16 * VALID] = awT;
        }
    }
}

// Blocks 0..863: one wave per active cell (n, i<3, j<3, k<3); lane = p1-subcell;
// fused nsplit reduction; butterfly sum. Blocks 864..988: constant fill.
__global__ __launch_bounds__(64) void pool_kernel(const float* __restrict__ C,
                                                  const float* __restrict__ wsB,
                                                  float* __restrict__ out,
                                                  int nsplit) {
    const int b = blockIdx.x;
    const int l = threadIdx.x;
    const float B = wsB[0];

    if (b < 864) {
        const int n = b / 27;
        const int cell = b - n * 27;
        const int ci = cell / 9, cj = (cell / 3) % 3, ck = cell % 3;
        float v = 0.f;
        if (l < 27) {
            const int da = l / 9, db = (l / 3) % 3, dc = l % 3;
            const int pz = 3 * ci + da, py = 3 * cj + db, px = 3 * ck + dc;
            const float* Cn = C + (size_t)n * CVOL;
            float m = -INFINITY;
            #pragma unroll
            for (int dz = 0; dz < 2; ++dz)
            #pragma unroll
            for (int dy = 0; dy < 2; ++dy)
            #pragma unroll
            for (int dx = 0; dx < 2; ++dx) {
                int z = 2 * pz + dz, y = 2 * py + dy, xx = 2 * px + dx;
                float t;
                if (z < VALID && y < VALID && xx < VALID) {
                    size_t off = ((size_t)z * VALID + y) * VALID + xx;
                    float sum = 0.f;
                    for (int ss = 0; ss < nsplit; ++ss)
                        sum += Cn[(size_t)ss * NB * CVOL + off];
                    t = sum + B;
                } else {
                    t = B;
                }
                m = fmaxf(m, t);
            }
            v = m;
        }
        #pragma unroll
        for (int off = 32; off > 0; off >>= 1) v += __shfl_xor(v, off, 64);
        if (l == 0) out[n * 1000 + ci * 100 + cj * 10 + ck] = v;
    } else {
        const int fb = b - 864;           // 0..124
        #pragma unroll
        for (int t = 0; t < 4; ++t) {
            int idx = fb * 256 + 64 * t + l;
            if (idx < 32000) {
                int r = idx % 1000;
                int i = r / 100, j = (r / 10) % 10, k = r % 10;
                if (i >= 3 || j >= 3 || k >= 3) out[idx] = 27.f * B;
            }
        }
    }
}

extern "C" void kernel_launch(void* const* d_in, const int* in_sizes, int n_in,
                              void* d_out, int out_size, void* d_ws, size_t ws_size,
                              hipStream_t stream) {
    const float* x      = (const float*)d_in[0];
    const float* weight = (const float*)d_in[1];
    const float* bias   = (const float*)d_in[2];
    float* out = (float*)d_out;
    float* ws  = (float*)d_ws;
    float* weff = ws;
    float* wsB  = ws + 4000;
    float* C    = ws + 4096;

    // nsplit=4: cpS=8 amortizes prologue; 768 blocks fully co-resident (4/CU x 256).
    int nsplit = 1;
    if      (ws_size >= (size_t)(4096 + 4 * NB * CVOL) * 4) nsplit = 4;
    else if (ws_size >= (size_t)(4096 + 2 * NB * CVOL) * 4) nsplit = 2;
    int cpS = CIN / nsplit;

    prep_kernel<<<dim3(16), dim3(256), 0, stream>>>(weight, bias, ws);
    conv_kernel<<<dim3(nsplit * NB * 6), dim3(384), 0, stream>>>(x, weff, C, cpS);
    pool_kernel<<<dim3(989), dim3(64), 0, stream>>>(C, wsB, out, nsplit);
}